// Round 1
// 2058.319 us; speedup vs baseline: 1.0379x; 1.0379x over previous
//
#include <hip/hip_runtime.h>

typedef unsigned short u16;
typedef __attribute__((ext_vector_type(8))) short short8;
typedef __attribute__((ext_vector_type(4))) float floatx4;

__device__ __forceinline__ u16 f2b(float f){
  unsigned u = __builtin_bit_cast(unsigned, f);
  u += 0x7FFFu + ((u >> 16) & 1u);   // RNE; inputs are finite
  return (u16)(u >> 16);
}

__device__ __forceinline__ float gelu_f(float x){
  float u = 0.7978845608028654f * (x + 0.044715f * x * x * x);
  float e = __expf(2.0f * u);                 // tanh(u) = 1 - 2/(e+1), robust at e=inf
  return 0.5f * x * (2.0f - 2.0f / (e + 1.0f));
}

// async global->LDS, 16B per lane (LDS dest = wave-uniform base + lane*16)
typedef const __attribute__((address_space(1))) unsigned int gas_u32;
typedef __attribute__((address_space(3))) unsigned int las_u32;
__device__ __forceinline__ void gll16(const void* g, void* l){
  __builtin_amdgcn_global_load_lds((gas_u32*)g, (las_u32*)l, 16, 0, 0);
}

// fp32 -> bf16 elementwise; 4 elems/thread
__global__ __launch_bounds__(256) void k_cvt(const float* __restrict__ src,
                                             u16* __restrict__ dst){
  size_t e = ((size_t)blockIdx.x * 256 + threadIdx.x) * 4;
  float4 v = *(const float4*)(src + e);
  ushort4 o; o.x = f2b(v.x); o.y = f2b(v.y); o.z = f2b(v.z); o.w = f2b(v.w);
  *(ushort4*)(dst + e) = o;
}

// h[b,t,c] = x[b,t,c] + wpe[t,c]
__global__ __launch_bounds__(256) void k_addpos(const float* __restrict__ x,
                                                const float* __restrict__ wpe,
                                                float* __restrict__ h){
  size_t e = ((size_t)blockIdx.x * 256 + threadIdx.x) * 4;
  float4 a = *(const float4*)(x + e);
  float4 p = *(const float4*)(wpe + (e & 1048575u));
  float4 o; o.x = a.x + p.x; o.y = a.y + p.y; o.z = a.z + p.z; o.w = a.w + p.w;
  *(float4*)(h + e) = o;
}

// LayerNorm over C=1024; out bf16 (GEMM input) or fp32 (final output)
__global__ __launch_bounds__(256) void k_layernorm(const float* __restrict__ x,
                                                   const float* __restrict__ w,
                                                   const float* __restrict__ b,
                                                   void* __restrict__ out, int out_bf16){
  int row = blockIdx.x, t = threadIdx.x;
  const float* xr = x + (size_t)row * 1024;
  float4 v = ((const float4*)xr)[t];
  float s1 = v.x + v.y + v.z + v.w;
  float s2 = v.x*v.x + v.y*v.y + v.z*v.z + v.w*v.w;
  #pragma unroll
  for (int off = 32; off > 0; off >>= 1){
    s1 += __shfl_down(s1, off);
    s2 += __shfl_down(s2, off);
  }
  __shared__ float p1[4], p2[4];
  if ((t & 63) == 0){ p1[t >> 6] = s1; p2[t >> 6] = s2; }
  __syncthreads();
  float S1 = p1[0] + p1[1] + p1[2] + p1[3];
  float S2 = p2[0] + p2[1] + p2[2] + p2[3];
  float mean = S1 * (1.0f / 1024.0f);
  float var  = S2 * (1.0f / 1024.0f) - mean * mean;
  float rs = rsqrtf(var + 1e-5f);
  float4 wv = ((const float4*)w)[t];
  float4 bv = ((const float4*)b)[t];
  float o0 = (v.x - mean) * rs * wv.x + bv.x;
  float o1 = (v.y - mean) * rs * wv.y + bv.y;
  float o2 = (v.z - mean) * rs * wv.z + bv.z;
  float o3 = (v.w - mean) * rs * wv.w + bv.w;
  if (out_bf16){
    ushort4 o; o.x = f2b(o0); o.y = f2b(o1); o.z = f2b(o2); o.w = f2b(o3);
    ((ushort4*)((u16*)out + (size_t)row * 1024))[t] = o;
  } else {
    float4 o; o.x = o0; o.y = o1; o.z = o2; o.w = o3;
    ((float4*)((float*)out + (size_t)row * 1024))[t] = o;
  }
}

// 128x128x(BK=32) bf16 GEMM, double-buffered LDS with prefetch (T3 2-phase):
// per K-iter issue next tile's global_load_lds BEFORE compute, single
// __syncthreads (vmcnt+lgkm drain + barrier) per iter. Overlaps load latency
// with MFMA within each wave -- matters here since grids are only 1.5-2
// blocks/CU (not enough TLP to hide latency the m97 way).
// C[m,n] = sum_k A[m,k]*B[n,k]  (both operands [rows, K] row-major bf16)
// MODE 0: bf16 = acc + bias    MODE 1: bf16 = gelu(acc + bias)
// MODE 2: fp32 atomicAdd(acc [+bias if sp==0])   (residual h += ...)
// MODE 3: QKV: n0<2048 like MODE 0 into Out; n0>=2048 (V cols) stored
//         TRANSPOSED into Out2 as vt[bh][d][s] (acc rows r are 4 consecutive
//         s at fixed d -> packed ushort4) -- replaces k_transpose_v.
// Split-K: bx -> nt = bx % n_ntiles (N tile), sp = bx / n_ntiles (K chunk).
template<int MODE>
__global__ __launch_bounds__(256) void k_gemm(
    const u16* __restrict__ A, int lda,
    const u16* __restrict__ B, int ldb,
    const float* __restrict__ bias,
    void* __restrict__ Out, int ldo,
    int Kdim, int n_ntiles, int Ksplit,
    u16* __restrict__ Out2)
{
  int bx = blockIdx.x, by = blockIdx.y;
  int nt = bx % n_ntiles, sp = bx / n_ntiles;
  int m0 = by * 128, n0 = nt * 128;
  int ks = sp * Ksplit;
  int ke = ks + Ksplit < Kdim ? ks + Ksplit : Kdim;
  if (ks >= ke) return;

  __shared__ u16 As[2][128 * 32];
  __shared__ u16 Bs[2][128 * 32];
  int t = threadIdx.x;
  int lane = t & 63, wid = t >> 6;
  int wm = (wid >> 1) * 64, wn = (wid & 1) * 64;
  int quad = lane >> 4, tm = lane & 15;
  int ar = t >> 2, ac = (t & 3) * 8;
  const u16* Ab = A + (size_t)(m0 + ar) * lda + ac;
  const u16* Bb = B + (size_t)(n0 + ar) * ldb + ac;
  const size_t a64 = (size_t)64 * lda, b64 = (size_t)64 * ldb;

  floatx4 acc[4][4] = {};
  // prologue: stage first tile into buffer 0
  gll16(Ab + ks,       &As[0][t * 8]);
  gll16(Ab + a64 + ks, &As[0][2048 + t * 8]);
  gll16(Bb + ks,       &Bs[0][t * 8]);
  gll16(Bb + b64 + ks, &Bs[0][2048 + t * 8]);
  __syncthreads();

  int cur = 0;
  for (int k0 = ks; k0 < ke; k0 += 32){
    int k1 = k0 + 32;
    if (k1 < ke){                       // prefetch next tile (block-uniform cond)
      gll16(Ab + k1,       &As[cur ^ 1][t * 8]);
      gll16(Ab + a64 + k1, &As[cur ^ 1][2048 + t * 8]);
      gll16(Bb + k1,       &Bs[cur ^ 1][t * 8]);
      gll16(Bb + b64 + k1, &Bs[cur ^ 1][2048 + t * 8]);
    }
    short8 af[4], bf[4];
    #pragma unroll
    for (int i = 0; i < 4; i++)
      af[i] = *(const short8*)&As[cur][(wm + i * 16 + tm) * 32 + quad * 8];
    #pragma unroll
    for (int j = 0; j < 4; j++)
      bf[j] = *(const short8*)&Bs[cur][(wn + j * 16 + tm) * 32 + quad * 8];
    #pragma unroll
    for (int i = 0; i < 4; i++)
      #pragma unroll
      for (int j = 0; j < 4; j++)
        acc[i][j] = __builtin_amdgcn_mfma_f32_16x16x32_bf16(af[i], bf[j], acc[i][j], 0, 0, 0);
    __syncthreads();                    // drains vmcnt(0)+lgkm; next buf ready
    cur ^= 1;
  }

  if (MODE == 3 && n0 >= 2048){
    // V columns: write transposed to vt[bh][d][s], ld_s = 1024.
    #pragma unroll
    for (int j = 0; j < 4; j++){
      int col = n0 + wn + j * 16 + tm;        // 2048..3071
      float bc = bias ? bias[col] : 0.0f;
      int dg = col - 2048;
      int hh = dg >> 7, d = dg & 127;
      #pragma unroll
      for (int i = 0; i < 4; i++){
        int row0 = m0 + wm + i * 16 + quad * 4;   // b*1024 + s, 4 consecutive s
        int b = row0 >> 10, s = row0 & 1023;
        ushort4 o;
        o.x = f2b(acc[i][j][0] + bc);
        o.y = f2b(acc[i][j][1] + bc);
        o.z = f2b(acc[i][j][2] + bc);
        o.w = f2b(acc[i][j][3] + bc);
        *(ushort4*)(Out2 + (size_t)(b * 8 + hh) * 131072 + (size_t)d * 1024 + s) = o;
      }
    }
  } else {
    #pragma unroll
    for (int j = 0; j < 4; j++){
      int col = n0 + wn + j * 16 + tm;
      float bc = 0.0f;
      if ((MODE == 0 || MODE == 1 || MODE == 3) && bias) bc = bias[col];
      if (MODE == 2 && sp == 0 && bias) bc = bias[col];
      #pragma unroll
      for (int i = 0; i < 4; i++){
        int row0 = m0 + wm + i * 16 + quad * 4;
        #pragma unroll
        for (int r = 0; r < 4; r++){
          float v = acc[i][j][r] + bc;
          size_t idx = (size_t)(row0 + r) * ldo + col;
          if (MODE == 0 || MODE == 3) ((u16*)Out)[idx] = f2b(v);
          else if (MODE == 1)         ((u16*)Out)[idx] = f2b(gelu_f(v));
          else                        atomicAdd((float*)Out + idx, v);
        }
      }
    }
  }
}

// Fused causal flash attention. Grid (16 q-tiles of 64 rows, 16 b*h).
// Per wave: 16 q-rows x full d=128. Q in regs; K/Vt tiles double-buffered in
// LDS with prefetch (1 barrier/iter); P round-trips via per-wave-private LDS
// region -- cross-wave barrier replaced by an lgkmcnt(0) drain.
__global__ __launch_bounds__(256) void k_flash(const u16* __restrict__ qkv,
                                               const u16* __restrict__ vt,
                                               u16* __restrict__ yb){
  int qi = blockIdx.x, bh = blockIdx.y;
  int b = bh >> 3, hh = bh & 7;
  int t = threadIdx.x, lane = t & 63, w = t >> 6;
  int quad = lane >> 4, tm = lane & 15;
  const int q0 = qi * 64;
  const u16* Qg  = qkv + (size_t)b * 3145728 + hh * 128;   // + row*3072
  const u16* Kg  = Qg + 1024;
  const u16* Vtg = vt + (size_t)bh * 131072;               // [d][s], ld=1024
  __shared__ u16 Ks[2][64 * 128];
  __shared__ u16 Vs[2][128 * 64];
  __shared__ u16 Ps[4][16 * 64];

  auto stage = [&](int s0s, int bufi){
    int idx = w * 256 + lane;
    #pragma unroll
    for (int p = 0; p < 4; p++){       // K tile: Ks[s(64)][d(128)]
      int id = idx + p * 64;
      gll16(Kg + (size_t)(s0s + (id >> 4)) * 3072 + (id & 15) * 8, &Ks[bufi][id * 8]);
    }
    #pragma unroll
    for (int p = 0; p < 4; p++){       // Vt tile: Vs[d(128)][s(64)]
      int id = idx + p * 64;
      gll16(Vtg + (size_t)(id >> 3) * 1024 + s0s + (id & 7) * 8, &Vs[bufi][id * 8]);
    }
  };

  short8 qf[4];
  {
    const u16* qr = Qg + (size_t)(q0 + w * 16 + tm) * 3072 + quad * 8;
    #pragma unroll
    for (int kk = 0; kk < 4; kk++) qf[kk] = *(const short8*)(qr + kk * 32);
  }
  floatx4 o_acc[8] = {};
  float m_r[4], l_r[4];
  #pragma unroll
  for (int r = 0; r < 4; r++){ m_r[r] = -3.0e38f; l_r[r] = 0.0f; }
  const float scale = 0.08838834764831845f;

  stage(0, 0);
  __syncthreads();
  int cur = 0;
  for (int s0 = 0; s0 <= q0; s0 += 64){
    if (s0 + 64 <= q0) stage(s0 + 64, cur ^ 1);  // prefetch next tile
    floatx4 s_acc[4] = {};
    #pragma unroll
    for (int j = 0; j < 4; j++)
      #pragma unroll
      for (int kk = 0; kk < 4; kk++){
        short8 kf = *(const short8*)&Ks[cur][(j * 16 + tm) * 128 + kk * 32 + quad * 8];
        s_acc[j] = __builtin_amdgcn_mfma_f32_16x16x32_bf16(qf[kk], kf, s_acc[j], 0, 0, 0);
      }
    bool diag = (s0 == q0);
    float sv[4][4];
    #pragma unroll
    for (int j = 0; j < 4; j++)
      #pragma unroll
      for (int r = 0; r < 4; r++){
        float v = s_acc[j][r] * scale;
        if (diag && (j * 16 + tm > w * 16 + quad * 4 + r)) v = -3.0e38f;
        sv[j][r] = v;
      }
    float pv[4][4];
    #pragma unroll
    for (int r = 0; r < 4; r++){
      float m = fmaxf(fmaxf(sv[0][r], sv[1][r]), fmaxf(sv[2][r], sv[3][r]));
      #pragma unroll
      for (int off = 8; off > 0; off >>= 1) m = fmaxf(m, __shfl_xor(m, off));
      float m_new = fmaxf(m_r[r], m);
      float alpha = __expf(m_r[r] - m_new);
      m_r[r] = m_new;
      float s = 0.0f;
      #pragma unroll
      for (int j = 0; j < 4; j++){
        float p = __expf(sv[j][r] - m_new);
        pv[j][r] = p; s += p;
      }
      #pragma unroll
      for (int off = 8; off > 0; off >>= 1) s += __shfl_xor(s, off);
      l_r[r] = l_r[r] * alpha + s;
      #pragma unroll
      for (int jd = 0; jd < 8; jd++) o_acc[jd][r] *= alpha;
    }
    // P: C-layout regs -> per-wave-private LDS -> A-layout frags.
    // No cross-wave barrier needed: Ps[w] is private; just drain LDS writes.
    u16* Pw = Ps[w];
    #pragma unroll
    for (int j = 0; j < 4; j++)
      #pragma unroll
      for (int r = 0; r < 4; r++)
        Pw[(quad * 4 + r) * 64 + j * 16 + tm] = f2b(pv[j][r]);
    asm volatile("s_waitcnt lgkmcnt(0)" ::: "memory");
    short8 pf[2];
    #pragma unroll
    for (int kk = 0; kk < 2; kk++)
      pf[kk] = *(const short8*)&Pw[tm * 64 + kk * 32 + quad * 8];
    #pragma unroll
    for (int jd = 0; jd < 8; jd++)
      #pragma unroll
      for (int kk = 0; kk < 2; kk++){
        short8 vf = *(const short8*)&Vs[cur][(jd * 16 + tm) * 64 + kk * 32 + quad * 8];
        o_acc[jd] = __builtin_amdgcn_mfma_f32_16x16x32_bf16(pf[kk], vf, o_acc[jd], 0, 0, 0);
      }
    __syncthreads();                   // next tile staged; Ks/Vs[cur] reusable
    cur ^= 1;
  }
  u16* yr = yb + ((size_t)b * 1024 + q0 + w * 16 + quad * 4) * 1024 + hh * 128;
  #pragma unroll
  for (int r = 0; r < 4; r++){
    float inv = 1.0f / l_r[r];
    #pragma unroll
    for (int jd = 0; jd < 8; jd++)
      yr[(size_t)r * 1024 + jd * 16 + tm] = f2b(o_acc[jd][r] * inv);
  }
}

extern "C" void kernel_launch(void* const* d_in, const int* in_sizes, int n_in,
                              void* d_out, int out_size, void* d_ws, size_t ws_size,
                              hipStream_t stream){
  const float* x     = (const float*)d_in[0];
  const float* wpe   = (const float*)d_in[1];
  const float* ln1w  = (const float*)d_in[2];
  const float* ln1b  = (const float*)d_in[3];
  const float* attnw = (const float*)d_in[4];
  const float* attnb = (const float*)d_in[5];
  const float* projw = (const float*)d_in[6];
  const float* projb = (const float*)d_in[7];
  const float* ln2w  = (const float*)d_in[8];
  const float* ln2b  = (const float*)d_in[9];
  const float* fcw   = (const float*)d_in[10];
  const float* fcb   = (const float*)d_in[11];
  const float* fcpw  = (const float*)d_in[12];
  const float* fcpb  = (const float*)d_in[13];
  const float* lnfw  = (const float*)d_in[14];
  const float* lnfb  = (const float*)d_in[15];

  char* ws = (char*)d_ws;                  // ws_size ~512 MB; we use 240 MB
  float* h    = (float*)(ws);              // 2048x1024 f32   (8 MB)
  u16*   xn   = (u16*)(ws + 8388608);      // 2048x1024 bf16  (4 MB)
  u16*   qkv  = (u16*)(ws + 12582912);     // 2048x3072 bf16  (12 MB)
  u16*   vt   = (u16*)(ws + 25165824);     // 16x128x1024 bf16 (4 MB)
  u16*   yb   = (u16*)(ws + 29360128);     // 2048x1024 bf16  (4 MB)
  u16*   mlp  = (u16*)(ws + 33554432);     // 2048x4096 bf16  (16 MB)
  u16*   wqkv = (u16*)(ws + 50331648);     // 8 x 3072x1024 bf16 (48 MB)
  u16*   wprj = (u16*)(ws + 100663296);    // 8 x 1024x1024 bf16 (16 MB)
  u16*   wfc  = (u16*)(ws + 117440512);    // 8 x 4096x1024 bf16 (64 MB)
  u16*   wfcp = (u16*)(ws + 184549376);    // 8 x 1024x4096 bf16 (64 MB) -> 240 MB

  // one-shot weight conversion (all layers)
  k_cvt<<<24576, 256, 0, stream>>>(attnw, wqkv);
  k_cvt<<<8192,  256, 0, stream>>>(projw, wprj);
  k_cvt<<<32768, 256, 0, stream>>>(fcw,  wfc);
  k_cvt<<<32768, 256, 0, stream>>>(fcpw, wfcp);
  k_addpos<<<2048, 256, 0, stream>>>(x, wpe, h);

  for (int l = 0; l < 8; l++){
    k_layernorm<<<2048, 256, 0, stream>>>(h, ln1w + l * 1024, ln1b + l * 1024, xn, 1);
    // QKV: [2048,1024] x [3072,1024]^T -> bf16 + bias; V cols transposed to vt
    k_gemm<3><<<dim3(24, 16), 256, 0, stream>>>(
        xn, 1024, wqkv + (size_t)l * 3145728, 1024, attnb + l * 3072,
        qkv, 3072, 1024, 24, 1024, vt);
    k_flash<<<dim3(16, 16), 256, 0, stream>>>(qkv, vt, yb);
    // proj: h += Y @ proj_w^T + b, split-K x4
    k_gemm<2><<<dim3(32, 16), 256, 0, stream>>>(
        yb, 1024, wprj + (size_t)l * 1048576, 1024, projb + l * 1024,
        h, 1024, 1024, 8, 256, (u16*)nullptr);
    k_layernorm<<<2048, 256, 0, stream>>>(h, ln2w + l * 1024, ln2b + l * 1024, xn, 1);
    // fc + gelu: [2048,1024] x [4096,1024]^T
    k_gemm<1><<<dim3(32, 16), 256, 0, stream>>>(
        xn, 1024, wfc + (size_t)l * 4194304, 1024, fcb + l * 4096,
        mlp, 4096, 1024, 32, 1024, (u16*)nullptr);
    // fc_proj: h += mlp @ fcp_w^T + b, split-K x4
    k_gemm<2><<<dim3(32, 16), 256, 0, stream>>>(
        mlp, 4096, wfcp + (size_t)l * 4194304, 4096, fcpb + l * 1024,
        h, 1024, 4096, 8, 1024, (u16*)nullptr);
  }
  k_layernorm<<<2048, 256, 0, stream>>>(h, lnfw, lnfb, (float*)d_out, 0);
  (void)in_sizes; (void)n_in; (void)out_size; (void)ws_size;
}

// Round 2
// 1858.827 us; speedup vs baseline: 1.1493x; 1.1073x over previous
//
#include <hip/hip_runtime.h>

typedef unsigned short u16;
typedef __attribute__((ext_vector_type(8))) short short8;
typedef __attribute__((ext_vector_type(4))) float floatx4;

__device__ __forceinline__ u16 f2b(float f){
  unsigned u = __builtin_bit_cast(unsigned, f);
  u += 0x7FFFu + ((u >> 16) & 1u);   // RNE; inputs are finite
  return (u16)(u >> 16);
}

__device__ __forceinline__ float gelu_f(float x){
  float u = 0.7978845608028654f * (x + 0.044715f * x * x * x);
  float e = __expf(2.0f * u);                 // tanh(u) = 1 - 2/(e+1), robust at e=inf
  return 0.5f * x * (2.0f - 2.0f / (e + 1.0f));
}

// async global->LDS, 16B per lane (LDS dest = wave-uniform base + lane*16)
typedef const __attribute__((address_space(1))) unsigned int gas_u32;
typedef __attribute__((address_space(3))) unsigned int las_u32;
__device__ __forceinline__ void gll16(const void* g, void* l){
  __builtin_amdgcn_global_load_lds((gas_u32*)g, (las_u32*)l, 16, 0, 0);
}

// fp32 -> bf16; 4 regions in one launch (saves 3 launch gaps)
__global__ __launch_bounds__(256) void k_cvt4(
    const float* __restrict__ s0, u16* __restrict__ d0,
    const float* __restrict__ s1, u16* __restrict__ d1,
    const float* __restrict__ s2, u16* __restrict__ d2,
    const float* __restrict__ s3, u16* __restrict__ d3){
  int blk = blockIdx.x;
  const float* s; u16* d; size_t bb;
  if      (blk < 24576){ s = s0; d = d0; bb = blk; }
  else if (blk < 32768){ s = s1; d = d1; bb = blk - 24576; }
  else if (blk < 65536){ s = s2; d = d2; bb = blk - 32768; }
  else                 { s = s3; d = d3; bb = blk - 65536; }
  size_t e = (bb * 256 + threadIdx.x) * 4;
  float4 v = *(const float4*)(s + e);
  ushort4 o; o.x = f2b(v.x); o.y = f2b(v.y); o.z = f2b(v.z); o.w = f2b(v.w);
  *(ushort4*)(d + e) = o;
}

// h[b,t,c] = x[b,t,c] + wpe[t,c]
__global__ __launch_bounds__(256) void k_addpos(const float* __restrict__ x,
                                                const float* __restrict__ wpe,
                                                float* __restrict__ h){
  size_t e = ((size_t)blockIdx.x * 256 + threadIdx.x) * 4;
  float4 a = *(const float4*)(x + e);
  float4 p = *(const float4*)(wpe + (e & 1048575u));
  float4 o; o.x = a.x + p.x; o.y = a.y + p.y; o.z = a.z + p.z; o.w = a.w + p.w;
  *(float4*)(h + e) = o;
}

// LayerNorm over C=1024; out bf16 (GEMM input) or fp32 (final output)
__global__ __launch_bounds__(256) void k_layernorm(const float* __restrict__ x,
                                                   const float* __restrict__ w,
                                                   const float* __restrict__ b,
                                                   void* __restrict__ out, int out_bf16){
  int row = blockIdx.x, t = threadIdx.x;
  const float* xr = x + (size_t)row * 1024;
  float4 v = ((const float4*)xr)[t];
  float s1 = v.x + v.y + v.z + v.w;
  float s2 = v.x*v.x + v.y*v.y + v.z*v.z + v.w*v.w;
  #pragma unroll
  for (int off = 32; off > 0; off >>= 1){
    s1 += __shfl_down(s1, off);
    s2 += __shfl_down(s2, off);
  }
  __shared__ float p1[4], p2[4];
  if ((t & 63) == 0){ p1[t >> 6] = s1; p2[t >> 6] = s2; }
  __syncthreads();
  float S1 = p1[0] + p1[1] + p1[2] + p1[3];
  float S2 = p2[0] + p2[1] + p2[2] + p2[3];
  float mean = S1 * (1.0f / 1024.0f);
  float var  = S2 * (1.0f / 1024.0f) - mean * mean;
  float rs = rsqrtf(var + 1e-5f);
  float4 wv = ((const float4*)w)[t];
  float4 bv = ((const float4*)b)[t];
  float o0 = (v.x - mean) * rs * wv.x + bv.x;
  float o1 = (v.y - mean) * rs * wv.y + bv.y;
  float o2 = (v.z - mean) * rs * wv.z + bv.z;
  float o3 = (v.w - mean) * rs * wv.w + bv.w;
  if (out_bf16){
    ushort4 o; o.x = f2b(o0); o.y = f2b(o1); o.z = f2b(o2); o.w = f2b(o3);
    ((ushort4*)((u16*)out + (size_t)row * 1024))[t] = o;
  } else {
    float4 o; o.x = o0; o.y = o1; o.z = o2; o.w = o3;
    ((float4*)((float*)out + (size_t)row * 1024))[t] = o;
  }
}

// 128x128x(BK=64) bf16 GEMM, double-buffered LDS + prefetch; one
// vmcnt-drain barrier per 64-K step (half the drains of BK=32), 32 MFMA per
// phase to cover load latency at the 1.5-2 block/CU grids this model has.
// LDS rows are 128B (worst bank alias), so staging pre-swizzles the GLOBAL
// source slot (dest stays linear for global_load_lds) and fragment reads
// XOR the same pattern: slot ^= row&7 (16B granularity).
// C[m,n] = sum_k A[m,k]*B[n,k]  (both operands [rows, K] row-major bf16)
// MODE 0: bf16 = acc + bias    MODE 1: bf16 = gelu(acc + bias)
// MODE 2: fp32 atomicAdd(acc [+bias if sp==0])   (residual h += ...)
// MODE 3: QKV: n0<2048 like MODE 0; n0>=2048 (V cols) stored TRANSPOSED
//         into Out2 as vt[bh][d][s] (fuses the V transpose).
// Split-K: bx -> nt = bx % n_ntiles (N tile), sp = bx / n_ntiles (K chunk).
template<int MODE>
__global__ __launch_bounds__(256) void k_gemm(
    const u16* __restrict__ A, int lda,
    const u16* __restrict__ B, int ldb,
    const float* __restrict__ bias,
    void* __restrict__ Out, int ldo,
    int Kdim, int n_ntiles, int Ksplit,
    u16* __restrict__ Out2)
{
  int bx = blockIdx.x, by = blockIdx.y;
  int nt = bx % n_ntiles, sp = bx / n_ntiles;
  int m0 = by * 128, n0 = nt * 128;
  int ks = sp * Ksplit;
  int ke = ks + Ksplit < Kdim ? ks + Ksplit : Kdim;
  if (ks >= ke) return;

  __shared__ u16 As[2][128 * 64];
  __shared__ u16 Bs[2][128 * 64];
  int t = threadIdx.x;
  int lane = t & 63, wid = t >> 6;
  int wm = (wid >> 1) * 64, wn = (wid & 1) * 64;
  int quad = lane >> 4, tm = lane & 15;
  // staging map: g = c*256+t -> row g>>3, 16B slot g&7 (linear LDS dest);
  // source slot pre-swizzled: sl ^ (row&7). row step 32 keeps row&7 fixed.
  int r0 = t >> 3, sl = t & 7;
  int scol = (sl ^ (r0 & 7)) * 8;
  const u16* Asrc = A + (size_t)(m0 + r0) * lda + scol;
  const u16* Bsrc = B + (size_t)(n0 + r0) * ldb + scol;
  const size_t a32 = (size_t)32 * lda, b32 = (size_t)32 * ldb;

  floatx4 acc[4][4] = {};
  // prologue: stage first K-tile into buffer 0
  #pragma unroll
  for (int c = 0; c < 4; c++){
    gll16(Asrc + c * a32 + ks, &As[0][c * 2048 + t * 8]);
    gll16(Bsrc + c * b32 + ks, &Bs[0][c * 2048 + t * 8]);
  }
  __syncthreads();

  int cur = 0;
  for (int k0 = ks; k0 < ke; k0 += 64){
    int k1 = k0 + 64;
    if (k1 < ke){                       // prefetch next tile (block-uniform cond)
      #pragma unroll
      for (int c = 0; c < 4; c++){
        gll16(Asrc + c * a32 + k1, &As[cur ^ 1][c * 2048 + t * 8]);
        gll16(Bsrc + c * b32 + k1, &Bs[cur ^ 1][c * 2048 + t * 8]);
      }
    }
    #pragma unroll
    for (int kk = 0; kk < 2; kk++){
      short8 af[4], bf[4];
      int cx = (kk * 32 + quad * 8) ^ ((tm & 7) << 3);
      #pragma unroll
      for (int i = 0; i < 4; i++)
        af[i] = *(const short8*)&As[cur][(wm + i * 16 + tm) * 64 + cx];
      #pragma unroll
      for (int j = 0; j < 4; j++)
        bf[j] = *(const short8*)&Bs[cur][(wn + j * 16 + tm) * 64 + cx];
      #pragma unroll
      for (int i = 0; i < 4; i++)
        #pragma unroll
        for (int j = 0; j < 4; j++)
          acc[i][j] = __builtin_amdgcn_mfma_f32_16x16x32_bf16(af[i], bf[j], acc[i][j], 0, 0, 0);
    }
    __syncthreads();                    // drains vmcnt(0)+lgkm; next buf ready
    cur ^= 1;
  }

  if (MODE == 3 && n0 >= 2048){
    // V columns: write transposed to vt[bh][d][s], ld_s = 1024.
    #pragma unroll
    for (int j = 0; j < 4; j++){
      int col = n0 + wn + j * 16 + tm;        // 2048..3071
      float bc = bias ? bias[col] : 0.0f;
      int dg = col - 2048;
      int hh = dg >> 7, d = dg & 127;
      #pragma unroll
      for (int i = 0; i < 4; i++){
        int row0 = m0 + wm + i * 16 + quad * 4;   // b*1024 + s, 4 consecutive s
        int b = row0 >> 10, s = row0 & 1023;
        ushort4 o;
        o.x = f2b(acc[i][j][0] + bc);
        o.y = f2b(acc[i][j][1] + bc);
        o.z = f2b(acc[i][j][2] + bc);
        o.w = f2b(acc[i][j][3] + bc);
        *(ushort4*)(Out2 + (size_t)(b * 8 + hh) * 131072 + (size_t)d * 1024 + s) = o;
      }
    }
  } else {
    #pragma unroll
    for (int j = 0; j < 4; j++){
      int col = n0 + wn + j * 16 + tm;
      float bc = 0.0f;
      if ((MODE == 0 || MODE == 1 || MODE == 3) && bias) bc = bias[col];
      if (MODE == 2 && sp == 0 && bias) bc = bias[col];
      #pragma unroll
      for (int i = 0; i < 4; i++){
        int row0 = m0 + wm + i * 16 + quad * 4;
        #pragma unroll
        for (int r = 0; r < 4; r++){
          float v = acc[i][j][r] + bc;
          size_t idx = (size_t)(row0 + r) * ldo + col;
          if (MODE == 0 || MODE == 3) ((u16*)Out)[idx] = f2b(v);
          else if (MODE == 1)         ((u16*)Out)[idx] = f2b(gelu_f(v));
          else                        atomicAdd((float*)Out + idx, v);
        }
      }
    }
  }
}

// Fused causal flash attention. Grid (16 q-tiles of 64 rows, 16 b*h).
// K/Vt/P LDS rows alias the 128B bank cycle -> all fragment reads XOR-swizzle
// the 16B slot with row&7 (source-side pre-swizzle for global_load_lds tiles,
// both-sides for the reg-staged P). setprio(1) around MFMA clusters.
__global__ __launch_bounds__(256) void k_flash(const u16* __restrict__ qkv,
                                               const u16* __restrict__ vt,
                                               u16* __restrict__ yb){
  int qi = blockIdx.x, bh = blockIdx.y;
  int b = bh >> 3, hh = bh & 7;
  int t = threadIdx.x, lane = t & 63, w = t >> 6;
  int quad = lane >> 4, tm = lane & 15;
  const int q0 = qi * 64;
  const u16* Qg  = qkv + (size_t)b * 3145728 + hh * 128;   // + row*3072
  const u16* Kg  = Qg + 1024;
  const u16* Vtg = vt + (size_t)bh * 131072;               // [d][s], ld=1024
  __shared__ u16 Ks[2][64 * 128];
  __shared__ u16 Vs[2][128 * 64];
  __shared__ u16 Ps[4][16 * 64];

  auto stage = [&](int s0s, int bufi){
    int idx = w * 256 + lane;
    #pragma unroll
    for (int p = 0; p < 4; p++){       // K tile: Ks[s(64)][d(128)], slot^=(s&7)
      int id = idx + p * 64;
      int s = id >> 4, slk = id & 15;
      gll16(Kg + (size_t)(s0s + s) * 3072 + ((slk ^ (s & 7)) * 8), &Ks[bufi][id * 8]);
    }
    #pragma unroll
    for (int p = 0; p < 4; p++){       // Vt tile: Vs[d(128)][s(64)], slot^=(d&7)
      int id = idx + p * 64;
      int d = id >> 3, slv = id & 7;
      gll16(Vtg + (size_t)d * 1024 + s0s + ((slv ^ (d & 7)) * 8), &Vs[bufi][id * 8]);
    }
  };

  short8 qf[4];
  {
    const u16* qr = Qg + (size_t)(q0 + w * 16 + tm) * 3072 + quad * 8;
    #pragma unroll
    for (int kk = 0; kk < 4; kk++) qf[kk] = *(const short8*)(qr + kk * 32);
  }
  floatx4 o_acc[8] = {};
  float m_r[4], l_r[4];
  #pragma unroll
  for (int r = 0; r < 4; r++){ m_r[r] = -3.0e38f; l_r[r] = 0.0f; }
  const float scale = 0.08838834764831845f;

  stage(0, 0);
  __syncthreads();
  int cur = 0;
  for (int s0 = 0; s0 <= q0; s0 += 64){
    if (s0 + 64 <= q0) stage(s0 + 64, cur ^ 1);  // prefetch next tile
    floatx4 s_acc[4] = {};
    __builtin_amdgcn_s_setprio(1);
    #pragma unroll
    for (int j = 0; j < 4; j++)
      #pragma unroll
      for (int kk = 0; kk < 4; kk++){
        short8 kf = *(const short8*)&Ks[cur][(j * 16 + tm) * 128 +
                        ((kk * 32 + quad * 8) ^ ((tm & 7) << 3))];
        s_acc[j] = __builtin_amdgcn_mfma_f32_16x16x32_bf16(qf[kk], kf, s_acc[j], 0, 0, 0);
      }
    __builtin_amdgcn_s_setprio(0);
    bool diag = (s0 == q0);
    float sv[4][4];
    #pragma unroll
    for (int j = 0; j < 4; j++)
      #pragma unroll
      for (int r = 0; r < 4; r++){
        float v = s_acc[j][r] * scale;
        if (diag && (j * 16 + tm > w * 16 + quad * 4 + r)) v = -3.0e38f;
        sv[j][r] = v;
      }
    float pv[4][4];
    #pragma unroll
    for (int r = 0; r < 4; r++){
      float m = fmaxf(fmaxf(sv[0][r], sv[1][r]), fmaxf(sv[2][r], sv[3][r]));
      #pragma unroll
      for (int off = 8; off > 0; off >>= 1) m = fmaxf(m, __shfl_xor(m, off));
      float m_new = fmaxf(m_r[r], m);
      float alpha = __expf(m_r[r] - m_new);
      m_r[r] = m_new;
      float s = 0.0f;
      #pragma unroll
      for (int j = 0; j < 4; j++){
        float p = __expf(sv[j][r] - m_new);
        pv[j][r] = p; s += p;
      }
      #pragma unroll
      for (int off = 8; off > 0; off >>= 1) s += __shfl_xor(s, off);
      l_r[r] = l_r[r] * alpha + s;
      #pragma unroll
      for (int jd = 0; jd < 8; jd++) o_acc[jd][r] *= alpha;
    }
    // P: C-layout regs -> per-wave-private LDS (swizzled both sides) -> A frags
    u16* Pw = Ps[w];
    #pragma unroll
    for (int j = 0; j < 4; j++)
      #pragma unroll
      for (int r = 0; r < 4; r++){
        int pr = quad * 4 + r;
        Pw[pr * 64 + ((j * 16 + tm) ^ ((pr & 7) << 3))] = f2b(pv[j][r]);
      }
    asm volatile("s_waitcnt lgkmcnt(0)" ::: "memory");
    short8 pf[2];
    #pragma unroll
    for (int kk = 0; kk < 2; kk++)
      pf[kk] = *(const short8*)&Pw[tm * 64 + ((kk * 32 + quad * 8) ^ ((tm & 7) << 3))];
    __builtin_amdgcn_s_setprio(1);
    #pragma unroll
    for (int jd = 0; jd < 8; jd++)
      #pragma unroll
      for (int kk = 0; kk < 2; kk++){
        short8 vf = *(const short8*)&Vs[cur][(jd * 16 + tm) * 64 +
                        ((kk * 32 + quad * 8) ^ ((tm & 7) << 3))];
        o_acc[jd] = __builtin_amdgcn_mfma_f32_16x16x32_bf16(pf[kk], vf, o_acc[jd], 0, 0, 0);
      }
    __builtin_amdgcn_s_setprio(0);
    __syncthreads();                   // next tile staged; Ks/Vs[cur] reusable
    cur ^= 1;
  }
  u16* yr = yb + ((size_t)b * 1024 + q0 + w * 16 + quad * 4) * 1024 + hh * 128;
  #pragma unroll
  for (int r = 0; r < 4; r++){
    float inv = 1.0f / l_r[r];
    #pragma unroll
    for (int jd = 0; jd < 8; jd++)
      yr[(size_t)r * 1024 + jd * 16 + tm] = f2b(o_acc[jd][r] * inv);
  }
}

extern "C" void kernel_launch(void* const* d_in, const int* in_sizes, int n_in,
                              void* d_out, int out_size, void* d_ws, size_t ws_size,
                              hipStream_t stream){
  const float* x     = (const float*)d_in[0];
  const float* wpe   = (const float*)d_in[1];
  const float* ln1w  = (const float*)d_in[2];
  const float* ln1b  = (const float*)d_in[3];
  const float* attnw = (const float*)d_in[4];
  const float* attnb = (const float*)d_in[5];
  const float* projw = (const float*)d_in[6];
  const float* projb = (const float*)d_in[7];
  const float* ln2w  = (const float*)d_in[8];
  const float* ln2b  = (const float*)d_in[9];
  const float* fcw   = (const float*)d_in[10];
  const float* fcb   = (const float*)d_in[11];
  const float* fcpw  = (const float*)d_in[12];
  const float* fcpb  = (const float*)d_in[13];
  const float* lnfw  = (const float*)d_in[14];
  const float* lnfb  = (const float*)d_in[15];

  char* ws = (char*)d_ws;                  // ws_size ~512 MB; we use 240 MB
  float* h    = (float*)(ws);              // 2048x1024 f32   (8 MB)
  u16*   xn   = (u16*)(ws + 8388608);      // 2048x1024 bf16  (4 MB)
  u16*   qkv  = (u16*)(ws + 12582912);     // 2048x3072 bf16  (12 MB)
  u16*   vt   = (u16*)(ws + 25165824);     // 16x128x1024 bf16 (4 MB)
  u16*   yb   = (u16*)(ws + 29360128);     // 2048x1024 bf16  (4 MB)
  u16*   mlp  = (u16*)(ws + 33554432);     // 2048x4096 bf16  (16 MB)
  u16*   wqkv = (u16*)(ws + 50331648);     // 8 x 3072x1024 bf16 (48 MB)
  u16*   wprj = (u16*)(ws + 100663296);    // 8 x 1024x1024 bf16 (16 MB)
  u16*   wfc  = (u16*)(ws + 117440512);    // 8 x 4096x1024 bf16 (64 MB)
  u16*   wfcp = (u16*)(ws + 184549376);    // 8 x 1024x4096 bf16 (64 MB) -> 240 MB

  // one-shot weight conversion (all layers, single launch)
  k_cvt4<<<98304, 256, 0, stream>>>(attnw, wqkv, projw, wprj, fcw, wfc, fcpw, wfcp);
  k_addpos<<<2048, 256, 0, stream>>>(x, wpe, h);

  for (int l = 0; l < 8; l++){
    k_layernorm<<<2048, 256, 0, stream>>>(h, ln1w + l * 1024, ln1b + l * 1024, xn, 1);
    // QKV: [2048,1024] x [3072,1024]^T -> bf16 + bias; V cols transposed to vt
    k_gemm<3><<<dim3(24, 16), 256, 0, stream>>>(
        xn, 1024, wqkv + (size_t)l * 3145728, 1024, attnb + l * 3072,
        qkv, 3072, 1024, 24, 1024, vt);
    k_flash<<<dim3(16, 16), 256, 0, stream>>>(qkv, vt, yb);
    // proj: h += Y @ proj_w^T + b, split-K x4
    k_gemm<2><<<dim3(32, 16), 256, 0, stream>>>(
        yb, 1024, wprj + (size_t)l * 1048576, 1024, projb + l * 1024,
        h, 1024, 1024, 8, 256, (u16*)nullptr);
    k_layernorm<<<2048, 256, 0, stream>>>(h, ln2w + l * 1024, ln2b + l * 1024, xn, 1);
    // fc + gelu: [2048,1024] x [4096,1024]^T
    k_gemm<1><<<dim3(32, 16), 256, 0, stream>>>(
        xn, 1024, wfc + (size_t)l * 4194304, 1024, fcb + l * 4096,
        mlp, 4096, 1024, 32, 1024, (u16*)nullptr);
    // fc_proj: h += mlp @ fcp_w^T + b, split-K x4
    k_gemm<2><<<dim3(32, 16), 256, 0, stream>>>(
        mlp, 4096, wfcp + (size_t)l * 4194304, 4096, fcpb + l * 1024,
        h, 1024, 4096, 8, 1024, (u16*)nullptr);
  }
  k_layernorm<<<2048, 256, 0, stream>>>(h, lnfw, lnfb, (float*)d_out, 0);
  (void)in_sizes; (void)n_in; (void)out_size; (void)ws_size;
}